// Round 6
// baseline (359.355 us; speedup 1.0000x reference)
//
#include <hip/hip_runtime.h>
#include <stdint.h>

#define TREES 8192
#define HID   256
#define CH    16
#define KL    4
#define G     8            // trees per group (r5's proven consumer tile)
#define NC    4            // groups per block
#define GB    (G * NC)     // 32 trees per block -> grid 256 = 1 block/CU
#define LDSS  264          // LDS row stride in bf16 elems (256 + 8 pad)

typedef short bf16x8 __attribute__((ext_vector_type(8)));
typedef float f32x4  __attribute__((ext_vector_type(4)));

__device__ __forceinline__ unsigned short f2bf(float f) {
    unsigned u = __builtin_bit_cast(unsigned, f);
    u += 0x7FFFu + ((u >> 16) & 1u);
    return (unsigned short)(u >> 16);
}
__device__ __forceinline__ float elu1(float x) {
    return x > 0.f ? x : (__expf(x) - 1.f);
}
__device__ __forceinline__ uint4 pack8(float4 a, float4 b) {
    union { uint4 u4; unsigned short s[8]; } U;
    U.s[0] = f2bf(a.x); U.s[1] = f2bf(a.y); U.s[2] = f2bf(a.z); U.s[3] = f2bf(a.w);
    U.s[4] = f2bf(b.x); U.s[5] = f2bf(b.y); U.s[6] = f2bf(b.z); U.s[7] = f2bf(b.w);
    return U.u4;
}

// ---- Prep: tiled transpose fp32 [h][d] -> bf16 [d][h], coalesced both sides.
// grid (4,4,5): z = 0..3 -> Wz layer k, z = 4 -> Wzf. Block (0,0,4) also does bzsum.
__global__ void prep_transpose(const float* __restrict__ Wz,
                               const float* __restrict__ Wzf,
                               const float* __restrict__ bz,
                               unsigned short* __restrict__ WzT,
                               unsigned short* __restrict__ WzfT,
                               float* __restrict__ bzsum) {
    __shared__ unsigned short ts[64][65];
    const int k  = blockIdx.z;
    const int h0 = blockIdx.x * 64;
    const int d0 = blockIdx.y * 64;
    const float* src = (k < KL) ? (Wz + (k << 16)) : Wzf;
    unsigned short* dst = (k < KL) ? (WzT + (k << 16)) : WzfT;
    const int tid = threadIdx.x;
    const int jc  = tid & 63;
    #pragma unroll
    for (int r = 0; r < 16; ++r) {
        int i = r * 4 + (tid >> 6);
        ts[jc][i] = f2bf(src[(h0 + i) * HID + d0 + jc]);   // coalesced read
    }
    __syncthreads();
    #pragma unroll
    for (int r = 0; r < 16; ++r) {
        int jl = r * 4 + (tid >> 6);
        dst[(d0 + jl) * HID + h0 + jc] = ts[jl][jc];       // coalesced write
    }
    if (k == KL && blockIdx.x == 0 && blockIdx.y == 0) {
        float s = 0.f;
        #pragma unroll
        for (int kk = 0; kk < KL; ++kk) s += bz[kk * HID + tid];
        bzsum[tid] = s;
    }
}

// ---- Main: producer/consumer wave specialization. 8 waves/block:
// waves 0-3 (consumers) run GEMM1+hsum on group c from A-buffer c&1;
// waves 4-7 (producers) gather group c+1 into A-buffer (c+1)&1 meanwhile.
// Gather latency hides under the MFMA phase (separate pipes, m114);
// consumer code & register profile are r5's proven spill-free versions.
__global__ __launch_bounds__(512, 2) void ptree_kernel(
    const float* __restrict__ x,               // [N,256] fp32
    const int* __restrict__ leaf,              // [T,16]
    const float* __restrict__ bzf,             // [256] fp32
    const unsigned short* __restrict__ WzT,    // [K][d][h] bf16 (ws)
    const unsigned short* __restrict__ WzfT,   // [d][h] bf16 (ws)
    const float* __restrict__ bzsum,           // [256] f32 (ws)
    float* __restrict__ out,                   // [T,256] fp32
    int nrows)
{
    __shared__ __align__(16) unsigned short sh[2][G][CH][LDSS]; // 135.2 KB
    __shared__ __align__(16) unsigned short hs[GB][LDSS];       // 16.9 KB
    const int tid  = threadIdx.x;
    const int lane = tid & 63;
    const int wave = tid >> 6;          // 0..7
    const int t0   = blockIdx.x * GB;
    const int ncol = lane & 15;
    const int quad = lane >> 4;
    const int dbase = (wave & 3) * 64;  // consumer d-slice (safe for producers)

    // ---- prologue: ALL 8 waves gather group 0 into sh[0] (4096 cells / 512 thr)
    #pragma unroll
    for (int i = 0; i < (G * CH * 32) / 512; ++i) {   // 8 iters
        int cid = i * 512 + tid;
        int g   = cid >> 9;
        int row = (cid >> 5) & 15;
        int ch  = cid & 31;
        int idx = leaf[(t0 + g) * CH + row];
        idx = ((unsigned)idx < (unsigned)nrows) ? idx : 0;
        const float* src = x + (size_t)idx * HID + ch * 8;
        float4 v0 = *(const float4*)src;
        float4 v1 = *(const float4*)(src + 4);
        *(uint4*)&sh[0][g][row][ch * 8] = pack8(v0, v1);
    }

    float bzs[4], bzfv[4];
    #pragma unroll
    for (int nt = 0; nt < 4; ++nt) {
        bzs[nt]  = bzsum[dbase + nt * 16 + ncol];
        bzfv[nt] = bzf[dbase + nt * 16 + ncol];
    }

    const unsigned short* wz_base = WzT + (dbase + ncol) * HID + quad * 8;

    __syncthreads();

    for (int c = 0; c < NC; ++c) {
        if (wave < 4) {
            // ================= CONSUMER: GEMM1 + hsum on group c ============
            f32x4 acc1[G][4];
            #pragma unroll
            for (int g = 0; g < G; ++g)
                #pragma unroll
                for (int nt = 0; nt < 4; ++nt) acc1[g][nt] = f32x4{0.f, 0.f, 0.f, 0.f};

            bf16x8 bc[4], bn[4];
            #pragma unroll
            for (int nt = 0; nt < 4; ++nt)
                bc[nt] = *(const bf16x8*)(wz_base + nt * 16 * HID);

            __builtin_amdgcn_s_setprio(1);    // T5: role diversity exists now
            #pragma unroll 2
            for (int s = 0; s < KL * 8; ++s) {
                const int sn = (s < KL * 8 - 1) ? s + 1 : s;
                const unsigned short* pn = wz_base + (sn >> 3) * 65536 + (sn & 7) * 32;
                #pragma unroll
                for (int nt = 0; nt < 4; ++nt)
                    bn[nt] = *(const bf16x8*)(pn + nt * 16 * HID);
                const int k    = s >> 3;
                const int kt   = s & 7;
                const int arow = (ncol - k) & 15;
                #pragma unroll
                for (int g = 0; g < G; ++g) {
                    bf16x8 a = *(const bf16x8*)&sh[c & 1][g][arow][kt * 32 + quad * 8];
                    #pragma unroll
                    for (int nt = 0; nt < 4; ++nt)
                        acc1[g][nt] = __builtin_amdgcn_mfma_f32_16x16x32_bf16(
                            a, bc[nt], acc1[g][nt], 0, 0, 0);
                }
                #pragma unroll
                for (int nt = 0; nt < 4; ++nt) bc[nt] = bn[nt];
            }
            __builtin_amdgcn_s_setprio(0);

            // hsum: +bz, ELU, sum over 16 children -> hs row (c*G+g)
            #pragma unroll
            for (int g = 0; g < G; ++g)
                #pragma unroll
                for (int nt = 0; nt < 4; ++nt) {
                    float sv = 0.f;
                    #pragma unroll
                    for (int r = 0; r < 4; ++r) sv += elu1(acc1[g][nt][r] + bzs[nt]);
                    sv += __shfl_xor(sv, 16);
                    sv += __shfl_xor(sv, 32);
                    if (quad == 0) hs[c * G + g][dbase + nt * 16 + ncol] = f2bf(sv);
                }
        } else if (c + 1 < NC) {
            // ================= PRODUCER: gather group c+1 ===================
            const int ptid = tid & 255;
            const int tg   = t0 + (c + 1) * G;
            #pragma unroll
            for (int i = 0; i < (G * CH * 32) / 256; ++i) {   // 16 iters
                int cid = i * 256 + ptid;
                int g   = cid >> 9;
                int row = (cid >> 5) & 15;
                int ch  = cid & 31;
                int idx = leaf[(tg + g) * CH + row];
                idx = ((unsigned)idx < (unsigned)nrows) ? idx : 0;
                const float* src = x + (size_t)idx * HID + ch * 8;
                float4 v0 = *(const float4*)src;
                float4 v1 = *(const float4*)(src + 4);
                *(uint4*)&sh[(c + 1) & 1][g][row][ch * 8] = pack8(v0, v1);
            }
        }
        __syncthreads();   // A[(c+1)&1] staged; hs rows of group c visible
    }

    // ---- GEMM2 (consumers only): 2 dense tiles of 16 trees each.
    if (wave < 4) {
        const unsigned short* wzf_base = WzfT + (dbase + ncol) * HID + quad * 8;
        #pragma unroll
        for (int t2 = 0; t2 < 2; ++t2) {
            f32x4 acc2[4];
            #pragma unroll
            for (int nt = 0; nt < 4; ++nt) acc2[nt] = f32x4{0.f, 0.f, 0.f, 0.f};

            #pragma unroll 2
            for (int kt = 0; kt < 8; ++kt) {
                bf16x8 a = *(const bf16x8*)&hs[t2 * 16 + ncol][kt * 32 + quad * 8];
                #pragma unroll
                for (int nt = 0; nt < 4; ++nt) {
                    bf16x8 b = *(const bf16x8*)(wzf_base + nt * 16 * HID + kt * 32);
                    acc2[nt] = __builtin_amdgcn_mfma_f32_16x16x32_bf16(
                        a, b, acc2[nt], 0, 0, 0);
                }
            }
            #pragma unroll
            for (int nt = 0; nt < 4; ++nt)
                #pragma unroll
                for (int r = 0; r < 4; ++r) {
                    const int tree = t2 * 16 + quad * 4 + r;   // all valid
                    float v = elu1(acc2[nt][r] + 16.f * bzfv[nt]);
                    out[(size_t)(t0 + tree) * HID + dbase + nt * 16 + ncol] = v;
                }
        }
    }
}

extern "C" void kernel_launch(void* const* d_in, const int* in_sizes, int n_in,
                              void* d_out, int out_size, void* d_ws, size_t ws_size,
                              hipStream_t stream) {
    (void)out_size; (void)ws_size;
    const void* p_x = nullptr; const void* p_Wz = nullptr; const void* p_bz = nullptr;
    const void* p_Wzf = nullptr; const void* p_bzf = nullptr; const void* p_leaf = nullptr;
    for (int i = 0; i < n_in; ++i) {
        switch (in_sizes[i]) {
            case 200000 * 256:   p_x    = d_in[i]; break;
            case KL * 256 * 256: p_Wz   = d_in[i]; break;
            case KL * 256:       p_bz   = d_in[i]; break;
            case 256 * 256:      p_Wzf  = d_in[i]; break;
            case 256:            p_bzf  = d_in[i]; break;
            case TREES * CH:     p_leaf = d_in[i]; break;
        }
    }
    const float* x    = (const float*)p_x;
    const float* Wz   = (const float*)p_Wz;
    const float* bz   = (const float*)p_bz;
    const float* Wzf  = (const float*)p_Wzf;
    const float* bzf  = (const float*)p_bzf;
    const int*   leaf = (const int*)p_leaf;

    unsigned short* WzT  = (unsigned short*)d_ws;        // 512 KB
    unsigned short* WzfT = WzT + KL * HID * HID;         // 128 KB
    float*          bzsum = (float*)(WzfT + HID * HID);  // 1 KB

    dim3 tg(4, 4, KL + 1);
    prep_transpose<<<tg, 256, 0, stream>>>(Wz, Wzf, bz, WzT, WzfT, bzsum);
    ptree_kernel<<<TREES / GB, 512, 0, stream>>>(x, leaf, bzf, WzT, WzfT, bzsum,
                                                 (float*)d_out, 200000);
}